// Round 7
// baseline (10991.120 us; speedup 1.0000x reference)
//
#include <hip/hip_runtime.h>
#include <hip/hip_bf16.h>
#include <stdint.h>

typedef __attribute__((ext_vector_type(8))) short bf16x8;
typedef __attribute__((ext_vector_type(4))) float f32x4;
typedef unsigned long long ull_t;

#define S_LEN 512
#define B_DIM 64
#define E_DIM 512
#define H_DIM 768
#define G4    3072      // 4H (one direction's gate width)
#define H2    1536      // 2H (combined hs row)
#define M_ROWS 32768    // S*B
#define CHUNK 128       // seq steps per X-chunk
#define CM    8192      // CHUNK*B rows per chunk
#define NSL   12        // col slices per batch group (64 cols = 16 words each)
#define WPR   192       // 8B words per h row (192*4 = 768 cols)

__device__ __forceinline__ float sigmf_(float x) { return 1.0f / (1.0f + __expf(-x)); }
__device__ __forceinline__ float tanhf2(float x) {
  x = fminf(fmaxf(x, -20.0f), 20.0f);
  float e = __expf(2.0f * x);
  return (e - 1.0f) / (e + 1.0f);
}
__device__ __forceinline__ float bfu(unsigned short u) { return __uint_as_float((unsigned)u << 16); }
__device__ __forceinline__ unsigned short packbf(float a) {
  __hip_bfloat16 t = __float2bfloat16(a);
  unsigned short b;
  __builtin_memcpy(&b, &t, 2);
  return b;
}

// ---------------- embedding gather + cast to bf16 ----------------
__global__ __launch_bounds__(256) void k_gather(const int* __restrict__ tokens,
                                                const float* __restrict__ emb,
                                                __hip_bfloat16* __restrict__ out) {
  const int t = blockIdx.x * 256 + threadIdx.x;
  const int e0 = t * 8;
  const int row = e0 >> 9;
  const int k = e0 & 511;
  const int tok = tokens[row];
  const float4* p = (const float4*)(emb + (size_t)tok * E_DIM + k);
  const float4 v0 = p[0], v1 = p[1];
  __align__(16) __hip_bfloat16 tmp[8];
  tmp[0] = __float2bfloat16(v0.x); tmp[1] = __float2bfloat16(v0.y);
  tmp[2] = __float2bfloat16(v0.z); tmp[3] = __float2bfloat16(v0.w);
  tmp[4] = __float2bfloat16(v1.x); tmp[5] = __float2bfloat16(v1.y);
  tmp[6] = __float2bfloat16(v1.z); tmp[7] = __float2bfloat16(v1.w);
  *(bf16x8*)(out + (size_t)t * 8) = *(const bf16x8*)tmp;
}

// ---------------- fp32 -> bf16 transpose (LDS tiled): dst[c*Rs+r]=src[r*Cs+c] ----------------
__global__ __launch_bounds__(256) void k_transpose_cast(const float* __restrict__ src,
                                                        __hip_bfloat16* __restrict__ dst,
                                                        int Rs, int Cs) {
  __shared__ float tile[32][33];
  const int tx = threadIdx.x & 31, ty = threadIdx.x >> 5;
  const int c0 = blockIdx.x * 32, r0 = blockIdx.y * 32;
  #pragma unroll
  for (int i = ty; i < 32; i += 8)
    tile[i][tx] = src[(size_t)(r0 + i) * Cs + c0 + tx];
  __syncthreads();
  #pragma unroll
  for (int i = ty; i < 32; i += 8)
    dst[(size_t)(c0 + i) * Rs + r0 + tx] = __float2bfloat16(tile[tx][i]);
}

// ---------------- combined bias for one direction: bi + bh ----------------
__global__ __launch_bounds__(256) void k_bias(const float* __restrict__ bi,
                                              const float* __restrict__ bh,
                                              float* __restrict__ bias) {
  const int n = blockIdx.x * 256 + threadIdx.x;
  bias[n] = bi[n] + bh[n];
}

// ---------------- chunk GEMM: Xc[8192,3072] = EmbChunk[8192,512] @ WiT^T + bias ----------------
__global__ __launch_bounds__(256) void k_gemm_x(const __hip_bfloat16* __restrict__ A,
                                                const __hip_bfloat16* __restrict__ BT,
                                                const float* __restrict__ bias,
                                                __hip_bfloat16* __restrict__ C) {
  __shared__ __align__(16) __hip_bfloat16 As[128][40];
  __shared__ __align__(16) __hip_bfloat16 Bs[128][40];
  const int tid = threadIdx.x;
  const int wave = tid >> 6, lane = tid & 63;
  const int q = lane >> 4, lr = lane & 15;
  const int wm = (wave >> 1) * 64, wn = (wave & 1) * 64;
  const int m0 = blockIdx.y * 128, n0 = blockIdx.x * 128;
  const int srow = tid >> 2, skseg = (tid & 3) * 8;

  f32x4 acc[4][4];
  #pragma unroll
  for (int i = 0; i < 4; ++i)
    #pragma unroll
    for (int j = 0; j < 4; ++j) { f32x4 z = {0.f, 0.f, 0.f, 0.f}; acc[i][j] = z; }

  for (int kt = 0; kt < 16; ++kt) {
    __syncthreads();
    const int kbase = kt * 32 + skseg;
    *(bf16x8*)&As[srow][skseg]      = *(const bf16x8*)(A + (size_t)(m0 + srow) * E_DIM + kbase);
    *(bf16x8*)&As[srow + 64][skseg] = *(const bf16x8*)(A + (size_t)(m0 + srow + 64) * E_DIM + kbase);
    *(bf16x8*)&Bs[srow][skseg]      = *(const bf16x8*)(BT + (size_t)(n0 + srow) * E_DIM + kbase);
    *(bf16x8*)&Bs[srow + 64][skseg] = *(const bf16x8*)(BT + (size_t)(n0 + srow + 64) * E_DIM + kbase);
    __syncthreads();
    bf16x8 af[4], bfr[4];
    #pragma unroll
    for (int mt = 0; mt < 4; ++mt) af[mt] = *(const bf16x8*)&As[wm + mt * 16 + lr][q * 8];
    #pragma unroll
    for (int nt = 0; nt < 4; ++nt) bfr[nt] = *(const bf16x8*)&Bs[wn + nt * 16 + lr][q * 8];
    #pragma unroll
    for (int mt = 0; mt < 4; ++mt)
      #pragma unroll
      for (int nt = 0; nt < 4; ++nt)
        acc[mt][nt] = __builtin_amdgcn_mfma_f32_16x16x32_bf16(af[mt], bfr[nt], acc[mt][nt], 0, 0, 0);
  }
  #pragma unroll
  for (int mt = 0; mt < 4; ++mt) {
    #pragma unroll
    for (int nt = 0; nt < 4; ++nt) {
      const int col = n0 + wn + nt * 16 + lr;
      const float bv = bias[col];
      #pragma unroll
      for (int i = 0; i < 4; ++i) {
        const int row = m0 + wm + mt * 16 + q * 4 + i;
        C[(size_t)row * G4 + col] = __float2bfloat16(acc[mt][nt][i] + bv);
      }
    }
  }
}

// ---------------- forward LSTM scan: systolic, flag + fragment-aligned data ----------------
// 48 WGs = 4 batch groups (16 rows) x 12 col-slices (64 cols = 16 words).
// h data: pure 8B words (4 bf16), relaxed agent atomics (IC-direct). Per-slice
// flags released after a vmcnt-draining __syncthreads. 12 lanes/wave poll the 12
// flags with s_sleep backoff (no congestion collapse). Staging = 12 aligned 8B
// loads + 12 ds_write_b64/thread (no unpacking).
__global__ __launch_bounds__(256, 1) void k_fwd_scan(const __hip_bfloat16* __restrict__ X,    // [8192,3072] chunk
                                                     const __hip_bfloat16* __restrict__ WhTf, // [3072,768]
                                                     ull_t* __restrict__ hbuf,                // [2][64][192] words
                                                     __hip_bfloat16* __restrict__ Hs,         // [32768,1536]
                                                     float* __restrict__ cstate,              // [64,768]
                                                     float* __restrict__ hT,                  // [64,768]
                                                     int* __restrict__ flags,                 // [4][12] @128B spacing
                                                     int chunk) {
  const int bx = blockIdx.x;
  const int group = bx / NSL;          // batch rows [16g, 16g+16)
  const int slice = bx % NSL;          // cols [64*slice, 64*slice+64)
  const int r0 = group * 16;
  const int j0 = slice * 64;
  const int tid = threadIdx.x;
  const int w = tid >> 6;              // wave = gate index (r,f,g,o)
  const int lane = tid & 63;
  const int q = lane >> 4, lr = lane & 15;
  const int base = chunk * CHUNK;

  const int row = tid >> 4;            // 0..15: batch row within group
  const int wl = tid & 15;             // 0..15: word lane
  const int col0 = 4 * wl;             // first owned col within slice

  __shared__ ull_t h_stage[16][WPR + 2];        // 24.8 KB; +2 words: bank skew
  __shared__ float g_lds[4][16][65];            // 16.6 KB

  // persistent c in registers: thread owns (row, col0..col0+3)
  float4 creg = *(const float4*)(cstate + (size_t)(r0 + row) * H_DIM + j0 + col0);

  int* flg = flags + group * NSL * 32;          // this group's 12 flag slots

  const __hip_bfloat16* wbase = WhTf + (size_t)w * H_DIM * H_DIM;  // gate w's rows

  for (int s = 0; s < CHUNK; ++s) {
    const int gs = base + s;

    // ---- X loads for this step (plain, L2-hot; independent of h) ----
    ull_t xw[4];
    {
      const ull_t* xp = (const ull_t*)(X + ((size_t)s * B_DIM + r0 + row) * G4 + j0 + col0);
      #pragma unroll
      for (int g = 0; g < 4; ++g) xw[g] = xp[g * (H_DIM / 4)];
    }

    // ---- poll the 12 slice flags (wave-synchronous, lanes 0..11, backoff) ----
    {
      long guard = 0;
      for (;;) {
        int v = gs;
        if (lane < NSL)
          v = __hip_atomic_load(&flg[lane * 32], __ATOMIC_RELAXED, __HIP_MEMORY_SCOPE_AGENT);
        if (__all(v >= gs)) break;
        if (++guard > 32) __builtin_amdgcn_s_sleep(1);
        if (guard > (1L << 21)) break;   // fail visibly, never hang
      }
      __asm__ volatile("" ::: "memory"); // no hoisting of data loads above poll
    }

    // ---- stage h_gs: 12 aligned 8B IC loads + 12 ds_write_b64 per thread ----
    {
      const ull_t* src = hbuf + ((size_t)(gs & 1) * (B_DIM * WPR)) + (size_t)(r0 + row) * WPR;
      #pragma unroll
      for (int i = 0; i < NSL; ++i) {
        const int wi = wl + 16 * i;
        h_stage[row][wi] =
            __hip_atomic_load(src + wi, __ATOMIC_RELAXED, __HIP_MEMORY_SCOPE_AGENT);
      }
    }
    __syncthreads();

    // ---- hidden GEMM for gate w: [16,768] x [768,64] -> 4 N-tiles ----
    f32x4 acc[4];
    #pragma unroll
    for (int nt = 0; nt < 4; ++nt) { f32x4 z = {0.f, 0.f, 0.f, 0.f}; acc[nt] = z; }
    #pragma unroll
    for (int kt = 0; kt < 24; ++kt) {
      const bf16x8 a = *(const bf16x8*)&h_stage[lr][kt * 8 + q * 2];
      const __hip_bfloat16* bp = wbase + (size_t)(j0 + lr) * H_DIM + kt * 32 + q * 8;
      #pragma unroll
      for (int nt = 0; nt < 4; ++nt) {
        const bf16x8 b = *(const bf16x8*)(bp + (size_t)nt * 16 * H_DIM);
        acc[nt] = __builtin_amdgcn_mfma_f32_16x16x32_bf16(a, b, acc[nt], 0, 0, 0);
      }
    }
    #pragma unroll
    for (int nt = 0; nt < 4; ++nt)
      #pragma unroll
      for (int i = 0; i < 4; ++i)
        g_lds[w][q * 4 + i][nt * 16 + lr] = acc[nt][i];
    __syncthreads();

    // ---- nonlinearity + c/h update: thread owns (row, col0..col0+3) ----
    {
      float h[4];
      float* cr = &creg.x;
      #pragma unroll
      for (int j = 0; j < 4; ++j) {
        const float rv = g_lds[0][row][col0 + j] + bfu((unsigned short)(xw[0] >> (16 * j)));
        const float fv = g_lds[1][row][col0 + j] + bfu((unsigned short)(xw[1] >> (16 * j)));
        const float gv = g_lds[2][row][col0 + j] + bfu((unsigned short)(xw[2] >> (16 * j)));
        const float ov = g_lds[3][row][col0 + j] + bfu((unsigned short)(xw[3] >> (16 * j)));
        const float c = sigmf_(fv) * cr[j] + sigmf_(rv) * tanhf2(gv);
        cr[j] = c;
        h[j] = sigmf_(ov) * tanhf2(c);
      }
      const ull_t pv = (ull_t)packbf(h[0]) | ((ull_t)packbf(h[1]) << 16)
                     | ((ull_t)packbf(h[2]) << 32) | ((ull_t)packbf(h[3]) << 48);
      __hip_atomic_store(hbuf + ((size_t)((gs + 1) & 1) * (B_DIM * WPR))
                              + (size_t)(r0 + row) * WPR + slice * 16 + wl,
                         pv, __ATOMIC_RELAXED, __HIP_MEMORY_SCOPE_AGENT);
      *(ull_t*)(Hs + ((size_t)gs * B_DIM + r0 + row) * H2 + j0 + col0) = pv;
      if (chunk == 3 && s == CHUNK - 1) {
        float* hp = hT + (size_t)(r0 + row) * H_DIM + j0 + col0;
        #pragma unroll
        for (int j = 0; j < 4; ++j) hp[j] = h[j];
      }
    }

    // ---- release this slice's flag (barrier drains all threads' h stores) ----
    __syncthreads();
    if (tid == 0)
      __hip_atomic_store(&flg[slice * 32], gs + 1, __ATOMIC_RELEASE, __HIP_MEMORY_SCOPE_AGENT);
  }

  // persist c for next chunk
  *(float4*)(cstate + (size_t)(r0 + row) * H_DIM + j0 + col0) = creg;
}

// ---------------- hTW[b,n] = hT[b,:] @ Wh_b[:,n] ----------------
__global__ __launch_bounds__(256) void k_hTW(const float* __restrict__ hT,
                                             const float* __restrict__ Whb,
                                             float* __restrict__ hTW) {
  const int b = blockIdx.y;
  const int n = blockIdx.x * 256 + threadIdx.x;
  __shared__ float hs[768];
  for (int i = threadIdx.x; i < 768; i += 256) hs[i] = hT[b * 768 + i];
  __syncthreads();
  float acc = 0.f;
  #pragma unroll 4
  for (int k = 0; k < 768; ++k) acc += hs[k] * Whb[(size_t)k * G4 + n];
  hTW[(size_t)b * G4 + n] = acc;
}

// ---------------- backward scan (one chunk, reverse): independent chains ----------------
__global__ __launch_bounds__(256) void k_bwd_scan(const __hip_bfloat16* __restrict__ X,
                                                  const float* __restrict__ hTW,
                                                  __hip_bfloat16* __restrict__ Hs,
                                                  float* __restrict__ c2state,
                                                  int chunk) {
  const int t = blockIdx.x * 256 + threadIdx.x;    // 49152
  const int b = t / H_DIM;
  const int j = t % H_DIM;
  const int base = chunk * CHUNK;
  const float hw0 = hTW[(size_t)b * G4 + j];
  const float hw1 = hTW[(size_t)b * G4 + 768 + j];
  const float hw2 = hTW[(size_t)b * G4 + 1536 + j];
  const float hw3 = hTW[(size_t)b * G4 + 2304 + j];
  float c2 = c2state[t];
  for (int s = CHUNK - 1; s >= 0; --s) {
    const size_t xb = ((size_t)s * B_DIM + b) * G4 + j;
    const float r = sigmf_(__bfloat162float(X[xb]) + hw0);
    const float f = sigmf_(__bfloat162float(X[xb + 768]) + hw1);
    const float g = tanhf2(__bfloat162float(X[xb + 1536]) + hw2);
    const float o = sigmf_(__bfloat162float(X[xb + 2304]) + hw3);
    c2 = f * c2 + r * g;
    Hs[((size_t)(base + s) * B_DIM + b) * H2 + H_DIM + j] = __float2bfloat16(o * tanhf2(c2));
  }
  c2state[t] = c2;
}

// ---------------- output: out[i,l] = Hs[i,:] @ Wout + bout (+pad bias) ----------------
__global__ __launch_bounds__(256) void k_out(const __hip_bfloat16* __restrict__ Hs,
                                             const float* __restrict__ Wout,
                                             const float* __restrict__ bout,
                                             const int* __restrict__ tokens,
                                             float* __restrict__ out) {
  __shared__ float rowbuf[8][1536];
  const int r0 = blockIdx.x * 8;
  const int tid = threadIdx.x;
  for (int idx = tid; idx < 8 * 1536; idx += 256) {
    const int rr = idx / 1536, k = idx % 1536;
    rowbuf[rr][k] = __bfloat162float(Hs[(size_t)(r0 + rr) * H2 + k]);
  }
  __syncthreads();
  const int l = tid & 31, rr = tid >> 5;
  float acc = bout[l];
  #pragma unroll 8
  for (int k = 0; k < 1536; ++k) acc += rowbuf[rr][k] * Wout[k * 32 + l];
  const int row = r0 + rr;
  if (l == 0 && tokens[row] == 1) acc += 10000.0f;
  out[(size_t)row * 32 + l] = acc;
}

// ---------------- host launcher ----------------
extern "C" void kernel_launch(void* const* d_in, const int* in_sizes, int n_in,
                              void* d_out, int out_size, void* d_ws, size_t ws_size,
                              hipStream_t stream) {
  const int*   tokens = (const int*)d_in[0];
  const float* emb    = (const float*)d_in[2];
  const float* Wi_f   = (const float*)d_in[3];
  const float* bi_f   = (const float*)d_in[4];
  const float* Wh_f   = (const float*)d_in[5];
  const float* bh_f   = (const float*)d_in[6];
  const float* Wi_b   = (const float*)d_in[7];
  const float* bi_b   = (const float*)d_in[8];
  const float* Wh_b   = (const float*)d_in[9];
  const float* bh_b   = (const float*)d_in[10];
  const float* Wout   = (const float*)d_in[11];
  const float* bout   = (const float*)d_in[12];
  float* out = (float*)d_out;
  char* ws = (char*)d_ws;

  size_t off = 0;
  auto alloc = [&](size_t bytes) { size_t o = off; off += (bytes + 255) & ~(size_t)255; return o; };
  const size_t oHs   = alloc((size_t)M_ROWS * H2 * 2);        // 100.7 MB
  const size_t oX    = alloc((size_t)CM * G4 * 2);            // 50.3 MB
  const size_t oEmb  = alloc((size_t)M_ROWS * E_DIM * 2);     // 33.6 MB
  const size_t oWiT  = alloc((size_t)G4 * E_DIM * 2);         // 3.1 MB
  const size_t oWhTf = alloc((size_t)G4 * H_DIM * 2);         // 4.7 MB
  const size_t oBias = alloc((size_t)G4 * 4);
  const size_t oHbuf = alloc((size_t)2 * B_DIM * WPR * 8);    // 196 KB packed h
  const size_t oCst  = alloc((size_t)B_DIM * H_DIM * 4);
  const size_t oHT   = alloc((size_t)B_DIM * H_DIM * 4);
  const size_t oHTW  = alloc((size_t)B_DIM * G4 * 4);
  const size_t oC2   = alloc((size_t)B_DIM * H_DIM * 4);
  const size_t oFlg  = alloc(4 * NSL * 32 * 4);               // 6 KB flags
  (void)ws_size; (void)in_sizes; (void)n_in; (void)out_size;   // total ~194 MB

  __hip_bfloat16* Hs   = (__hip_bfloat16*)(ws + oHs);
  __hip_bfloat16* X    = (__hip_bfloat16*)(ws + oX);
  __hip_bfloat16* Emb  = (__hip_bfloat16*)(ws + oEmb);
  __hip_bfloat16* WiT  = (__hip_bfloat16*)(ws + oWiT);
  __hip_bfloat16* WhTf = (__hip_bfloat16*)(ws + oWhTf);
  float*          Bias = (float*)(ws + oBias);
  ull_t*          Hbuf = (ull_t*)(ws + oHbuf);
  float*          Cst  = (float*)(ws + oCst);
  float*          HT   = (float*)(ws + oHT);
  float*          HTW  = (float*)(ws + oHTW);
  float*          C2   = (float*)(ws + oC2);
  int*            Flg  = (int*)(ws + oFlg);

  hipMemsetAsync(ws + oHbuf, 0, (size_t)2 * B_DIM * WPR * 8, stream);  // h_0 = 0
  hipMemsetAsync(ws + oCst, 0, (size_t)B_DIM * H_DIM * 4, stream);
  hipMemsetAsync(ws + oC2, 0, (size_t)B_DIM * H_DIM * 4, stream);
  hipMemsetAsync(ws + oFlg, 0, 4 * NSL * 32 * 4, stream);              // flags = 0

  k_gather<<<8192, 256, 0, stream>>>(tokens, emb, Emb);
  k_transpose_cast<<<dim3(96, 24), 256, 0, stream>>>(Wh_f, WhTf, 768, 3072);

  // ---- forward direction: 4 chunks of (GEMM -> scan) ----
  k_transpose_cast<<<dim3(96, 16), 256, 0, stream>>>(Wi_f, WiT, 512, 3072);
  k_bias<<<12, 256, 0, stream>>>(bi_f, bh_f, Bias);
  for (int c = 0; c < 4; ++c) {
    k_gemm_x<<<dim3(24, 64), 256, 0, stream>>>(Emb + (size_t)c * CM * E_DIM, WiT, Bias, X);
    k_fwd_scan<<<48, 256, 0, stream>>>(X, WhTf, Hbuf, Hs, Cst, HT, Flg, c);
  }

  // ---- backward direction: hT@Wh_b once, then 4 chunks in reverse ----
  k_hTW<<<dim3(12, 64), 256, 0, stream>>>(HT, Wh_b, HTW);
  k_transpose_cast<<<dim3(96, 16), 256, 0, stream>>>(Wi_b, WiT, 512, 3072);
  k_bias<<<12, 256, 0, stream>>>(bi_b, bh_b, Bias);
  for (int c = 3; c >= 0; --c) {
    k_gemm_x<<<dim3(24, 64), 256, 0, stream>>>(Emb + (size_t)c * CM * E_DIM, WiT, Bias, X);
    k_bwd_scan<<<192, 256, 0, stream>>>(X, HTW, Hs, C2, c);
  }

  k_out<<<4096, 256, 0, stream>>>(Hs, Wout, bout, tokens, out);
}

// Round 8
// 4410.516 us; speedup vs baseline: 2.4920x; 2.4920x over previous
//
#include <hip/hip_runtime.h>
#include <hip/hip_bf16.h>
#include <stdint.h>

typedef __attribute__((ext_vector_type(8))) short bf16x8;
typedef __attribute__((ext_vector_type(4))) float f32x4;
typedef unsigned long long ull_t;

#define S_LEN 512
#define B_DIM 64
#define E_DIM 512
#define H_DIM 768
#define G4    3072      // 4H (one direction's gate width)
#define H2    1536      // 2H (combined hs row)
#define M_ROWS 32768    // S*B
#define CHUNK 128       // seq steps per X-chunk
#define CM    8192      // CHUNK*B rows per chunk
#define WPR   256       // packed 8B words per h row (256*3 = 768 cols)

__device__ __forceinline__ float sigmf_(float x) { return 1.0f / (1.0f + __expf(-x)); }
__device__ __forceinline__ float tanhf2(float x) {
  x = fminf(fmaxf(x, -20.0f), 20.0f);
  float e = __expf(2.0f * x);
  return (e - 1.0f) / (e + 1.0f);
}
__device__ __forceinline__ float bfu(unsigned short u) { return __uint_as_float((unsigned)u << 16); }
__device__ __forceinline__ unsigned short packbf(float a) {
  __hip_bfloat16 t = __float2bfloat16(a);
  unsigned short b;
  __builtin_memcpy(&b, &t, 2);
  return b;
}

// ---------------- embedding gather + cast to bf16 ----------------
__global__ __launch_bounds__(256) void k_gather(const int* __restrict__ tokens,
                                                const float* __restrict__ emb,
                                                __hip_bfloat16* __restrict__ out) {
  const int t = blockIdx.x * 256 + threadIdx.x;
  const int e0 = t * 8;
  const int row = e0 >> 9;
  const int k = e0 & 511;
  const int tok = tokens[row];
  const float4* p = (const float4*)(emb + (size_t)tok * E_DIM + k);
  const float4 v0 = p[0], v1 = p[1];
  __align__(16) __hip_bfloat16 tmp[8];
  tmp[0] = __float2bfloat16(v0.x); tmp[1] = __float2bfloat16(v0.y);
  tmp[2] = __float2bfloat16(v0.z); tmp[3] = __float2bfloat16(v0.w);
  tmp[4] = __float2bfloat16(v1.x); tmp[5] = __float2bfloat16(v1.y);
  tmp[6] = __float2bfloat16(v1.z); tmp[7] = __float2bfloat16(v1.w);
  *(bf16x8*)(out + (size_t)t * 8) = *(const bf16x8*)tmp;
}

// ---------------- fp32 -> bf16 transpose (LDS tiled): dst[c*Rs+r]=src[r*Cs+c] ----------------
__global__ __launch_bounds__(256) void k_transpose_cast(const float* __restrict__ src,
                                                        __hip_bfloat16* __restrict__ dst,
                                                        int Rs, int Cs) {
  __shared__ float tile[32][33];
  const int tx = threadIdx.x & 31, ty = threadIdx.x >> 5;
  const int c0 = blockIdx.x * 32, r0 = blockIdx.y * 32;
  #pragma unroll
  for (int i = ty; i < 32; i += 8)
    tile[i][tx] = src[(size_t)(r0 + i) * Cs + c0 + tx];
  __syncthreads();
  #pragma unroll
  for (int i = ty; i < 32; i += 8)
    dst[(size_t)(c0 + i) * Rs + r0 + tx] = __float2bfloat16(tile[tx][i]);
}

// ---------------- slot-padded recurrent weights ----------------
// WhTf: [3072 rows = g*768+col][768 k]  ->  WhP: [4096 rows = g*1024+slot][768 k]
// slot%4==0 rows are ZERO (they align with the tag position of packed h words).
__global__ __launch_bounds__(256) void k_wpad(const __hip_bfloat16* __restrict__ WhTf,
                                              __hip_bfloat16* __restrict__ WhP) {
  const int t = blockIdx.x * 256 + threadIdx.x;   // 4096*96 = 393216 threads
  const int row = t / 96;                         // 0..4095
  const int ch = t % 96;                          // 16B chunk within 768 shorts
  const int g = row >> 10, slot = row & 1023;
  uint4 val = {0u, 0u, 0u, 0u};
  if (slot & 3) {
    const int col = 3 * (slot >> 2) + (slot & 3) - 1;
    val = ((const uint4*)WhTf)[(size_t)(g * 768 + col) * 96 + ch];
  }
  ((uint4*)WhP)[(size_t)row * 96 + ch] = val;
}

// ---------------- combined bias for one direction: bi + bh ----------------
__global__ __launch_bounds__(256) void k_bias(const float* __restrict__ bi,
                                              const float* __restrict__ bh,
                                              float* __restrict__ bias) {
  const int n = blockIdx.x * 256 + threadIdx.x;
  bias[n] = bi[n] + bh[n];
}

// ---------------- chunk GEMM: Xc[8192,3072] = EmbChunk[8192,512] @ WiT^T + bias ----------------
__global__ __launch_bounds__(256) void k_gemm_x(const __hip_bfloat16* __restrict__ A,
                                                const __hip_bfloat16* __restrict__ BT,
                                                const float* __restrict__ bias,
                                                __hip_bfloat16* __restrict__ C) {
  __shared__ __align__(16) __hip_bfloat16 As[128][40];
  __shared__ __align__(16) __hip_bfloat16 Bs[128][40];
  const int tid = threadIdx.x;
  const int wave = tid >> 6, lane = tid & 63;
  const int q = lane >> 4, lr = lane & 15;
  const int wm = (wave >> 1) * 64, wn = (wave & 1) * 64;
  const int m0 = blockIdx.y * 128, n0 = blockIdx.x * 128;
  const int srow = tid >> 2, skseg = (tid & 3) * 8;

  f32x4 acc[4][4];
  #pragma unroll
  for (int i = 0; i < 4; ++i)
    #pragma unroll
    for (int j = 0; j < 4; ++j) { f32x4 z = {0.f, 0.f, 0.f, 0.f}; acc[i][j] = z; }

  for (int kt = 0; kt < 16; ++kt) {
    __syncthreads();
    const int kbase = kt * 32 + skseg;
    *(bf16x8*)&As[srow][skseg]      = *(const bf16x8*)(A + (size_t)(m0 + srow) * E_DIM + kbase);
    *(bf16x8*)&As[srow + 64][skseg] = *(const bf16x8*)(A + (size_t)(m0 + srow + 64) * E_DIM + kbase);
    *(bf16x8*)&Bs[srow][skseg]      = *(const bf16x8*)(BT + (size_t)(n0 + srow) * E_DIM + kbase);
    *(bf16x8*)&Bs[srow + 64][skseg] = *(const bf16x8*)(BT + (size_t)(n0 + srow + 64) * E_DIM + kbase);
    __syncthreads();
    bf16x8 af[4], bfr[4];
    #pragma unroll
    for (int mt = 0; mt < 4; ++mt) af[mt] = *(const bf16x8*)&As[wm + mt * 16 + lr][q * 8];
    #pragma unroll
    for (int nt = 0; nt < 4; ++nt) bfr[nt] = *(const bf16x8*)&Bs[wn + nt * 16 + lr][q * 8];
    #pragma unroll
    for (int mt = 0; mt < 4; ++mt)
      #pragma unroll
      for (int nt = 0; nt < 4; ++nt)
        acc[mt][nt] = __builtin_amdgcn_mfma_f32_16x16x32_bf16(af[mt], bfr[nt], acc[mt][nt], 0, 0, 0);
  }
  #pragma unroll
  for (int mt = 0; mt < 4; ++mt) {
    #pragma unroll
    for (int nt = 0; nt < 4; ++nt) {
      const int col = n0 + wn + nt * 16 + lr;
      const float bv = bias[col];
      #pragma unroll
      for (int i = 0; i < 4; ++i) {
        const int row = m0 + wm + mt * 16 + q * 4 + i;
        C[(size_t)row * G4 + col] = __float2bfloat16(acc[mt][nt][i] + bv);
      }
    }
  }
}

// ---------------- forward LSTM scan: tag-in-data systolic, producer-direct words -------------
// 64 WGs = 4 batch groups (16 rows) x 16 col-slices (48 cols = 16 words).
// TRANSPOSED hidden GEMM D[col-slot][batch-row] with slot-padded weights: each lane's
// C quad = [tag slot | 3 cols] of ONE row -> pack + agent-store DIRECTLY from MFMA
// accumulators (no g_lds exchange). X folded in as the MFMA C-initializer.
// Consumers poll the data words' embedded tag (ONE IC round trip), s_sleep-throttled.
__global__ __launch_bounds__(256, 1) void k_fwd_scan(const __hip_bfloat16* __restrict__ X,   // [8192,3072] chunk
                                                     const __hip_bfloat16* __restrict__ WhP, // [4096,768] padded
                                                     ull_t* __restrict__ hbuf,               // [2][64][256] words
                                                     __hip_bfloat16* __restrict__ Hs,        // [32768,1536]
                                                     float* __restrict__ cstate,             // [64,768]
                                                     float* __restrict__ hT,                 // [64,768]
                                                     int chunk) {
  const int bx = blockIdx.x;
  const int group = bx >> 4;           // batch rows [16g, 16g+16)
  const int slice = bx & 15;           // cols [48*slice, 48*slice+48) = words [16*slice, +16)
  const int r0 = group * 16;
  const int tid = threadIdx.x;
  const int w = tid >> 6;              // wave = m-tile index (words 4w..4w+3 of slice)
  const int lane = tid & 63;
  const int q = lane >> 4, lr = lane & 15;
  const int base = chunk * CHUNK;

  const int row = tid >> 4;            // staging: batch row within group
  const int wl = tid & 15;             // staging: word lane

  __shared__ unsigned short h_stage[16][776];   // stripped bf16 bits, padded rows (24.8 KB)

  // this lane's produced word: word index within row, and its 3 global cols
  const int wword = slice * 16 + w * 4 + q;     // 0..255
  const int cb = 3 * wword;                     // first col (0..765)

  // persistent c in registers: thread owns (row lr, cols cb..cb+2)
  float cr[3];
  {
    const float* cs = cstate + (size_t)(r0 + lr) * H_DIM + cb;
    cr[0] = cs[0]; cr[1] = cs[1]; cr[2] = cs[2];
  }

  // weight row pointer for this lane: slot row = 64*slice + 16*w + lr, k-seg q*8
  const __hip_bfloat16* wrow = WhP + ((size_t)(slice * 64 + w * 16 + lr)) * H_DIM + q * 8;

  for (int s = 0; s < CHUNK; ++s) {
    const int gs = base + s;

    // ---- X loads for this step (L2-hot, overlap the poll) ----
    unsigned short xs[4][3];
    {
      const unsigned short* xp = (const unsigned short*)(X + ((size_t)s * B_DIM + r0 + lr) * G4 + cb);
      #pragma unroll
      for (int g = 0; g < 4; ++g)
        #pragma unroll
        for (int j = 0; j < 3; ++j) xs[g][j] = xp[g * H_DIM + j];
    }

    // ---- poll + load h_gs words (tag == gs), throttled retries ----
    {
      const ull_t* hc = hbuf + ((size_t)(gs & 1) << 14) + (size_t)(r0 + row) * WPR + wl;
      ull_t v[16];
      const unsigned short expct = (unsigned short)gs;
      unsigned need = 0xFFFFu;
      long guard = 0;
      for (;;) {
        #pragma unroll
        for (int i = 0; i < 16; ++i)
          if (need & (1u << i))
            v[i] = __hip_atomic_load(hc + 16 * i, __ATOMIC_RELAXED, __HIP_MEMORY_SCOPE_AGENT);
        unsigned nn = 0;
        #pragma unroll
        for (int i = 0; i < 16; ++i)
          if ((need & (1u << i)) && ((unsigned short)v[i] != expct)) nn |= 1u << i;
        need = nn;
        if (!need) break;
        __builtin_amdgcn_s_sleep(2);         // throttle retry storms (R6 outlier fix)
        if (++guard > (1L << 20)) break;     // fail visibly, never hang
      }
      // strip tags into clean row-major LDS
      #pragma unroll
      for (int i = 0; i < 16; ++i) {
        const int cc = 3 * (wl + 16 * i);
        const ull_t x = v[i];
        h_stage[row][cc]     = (unsigned short)(x >> 16);
        h_stage[row][cc + 1] = (unsigned short)(x >> 32);
        h_stage[row][cc + 2] = (unsigned short)(x >> 48);
      }
    }
    __syncthreads();

    // ---- transposed hidden GEMM: D[slot][row], acc init = X gates ----
    f32x4 acc[4];
    #pragma unroll
    for (int g = 0; g < 4; ++g) {
      acc[g][0] = 0.0f;                       // tag slot (zero weight row)
      acc[g][1] = bfu(xs[g][0]);
      acc[g][2] = bfu(xs[g][1]);
      acc[g][3] = bfu(xs[g][2]);
    }
    #pragma unroll
    for (int kt = 0; kt < 24; ++kt) {
      const bf16x8 hf = *(const bf16x8*)&h_stage[lr][kt * 32 + q * 8];
      #pragma unroll
      for (int g = 0; g < 4; ++g) {
        const bf16x8 wf = *(const bf16x8*)(wrow + (size_t)g * (1024 * H_DIM) + kt * 32);
        acc[g] = __builtin_amdgcn_mfma_f32_16x16x32_bf16(wf, hf, acc[g], 0, 0, 0);
      }
    }

    // ---- nonlinearity + c/h update straight from accumulators; store ASAP ----
    {
      float h[3];
      #pragma unroll
      for (int i = 1; i <= 3; ++i) {
        const float c = sigmf_(acc[1][i]) * cr[i - 1] + sigmf_(acc[0][i]) * tanhf2(acc[2][i]);
        cr[i - 1] = c;
        h[i - 1] = sigmf_(acc[3][i]) * tanhf2(c);
      }
      const unsigned short b0 = packbf(h[0]), b1 = packbf(h[1]), b2 = packbf(h[2]);
      const ull_t wv = (ull_t)(unsigned short)(gs + 1)
                     | ((ull_t)b0 << 16) | ((ull_t)b1 << 32) | ((ull_t)b2 << 48);
      __hip_atomic_store(hbuf + ((size_t)((gs + 1) & 1) << 14) + (size_t)(r0 + lr) * WPR + wword,
                         wv, __ATOMIC_RELAXED, __HIP_MEMORY_SCOPE_AGENT);
      unsigned short* hsp = (unsigned short*)(Hs + ((size_t)gs * B_DIM + r0 + lr) * H2 + cb);
      hsp[0] = b0; hsp[1] = b1; hsp[2] = b2;
      if (chunk == 3 && s == CHUNK - 1) {
        float* hp = hT + (size_t)(r0 + lr) * H_DIM + cb;
        hp[0] = h[0]; hp[1] = h[1]; hp[2] = h[2];
      }
    }

    // protect h_stage against next iteration's staging writes
    __syncthreads();
  }

  // persist c for next chunk
  {
    float* cs = cstate + (size_t)(r0 + lr) * H_DIM + cb;
    cs[0] = cr[0]; cs[1] = cr[1]; cs[2] = cr[2];
  }
}

// ---------------- hTW[b,n] = hT[b,:] @ Wh_b[:,n] ----------------
__global__ __launch_bounds__(256) void k_hTW(const float* __restrict__ hT,
                                             const float* __restrict__ Whb,
                                             float* __restrict__ hTW) {
  const int b = blockIdx.y;
  const int n = blockIdx.x * 256 + threadIdx.x;
  __shared__ float hs[768];
  for (int i = threadIdx.x; i < 768; i += 256) hs[i] = hT[b * 768 + i];
  __syncthreads();
  float acc = 0.f;
  #pragma unroll 4
  for (int k = 0; k < 768; ++k) acc += hs[k] * Whb[(size_t)k * G4 + n];
  hTW[(size_t)b * G4 + n] = acc;
}

// ---------------- backward scan (one chunk, reverse): independent chains ----------------
__global__ __launch_bounds__(256) void k_bwd_scan(const __hip_bfloat16* __restrict__ X,
                                                  const float* __restrict__ hTW,
                                                  __hip_bfloat16* __restrict__ Hs,
                                                  float* __restrict__ c2state,
                                                  int chunk) {
  const int t = blockIdx.x * 256 + threadIdx.x;    // 49152
  const int b = t / H_DIM;
  const int j = t % H_DIM;
  const int base = chunk * CHUNK;
  const float hw0 = hTW[(size_t)b * G4 + j];
  const float hw1 = hTW[(size_t)b * G4 + 768 + j];
  const float hw2 = hTW[(size_t)b * G4 + 1536 + j];
  const float hw3 = hTW[(size_t)b * G4 + 2304 + j];
  float c2 = c2state[t];
  for (int s = CHUNK - 1; s >= 0; --s) {
    const size_t xb = ((size_t)s * B_DIM + b) * G4 + j;
    const float r = sigmf_(__bfloat162float(X[xb]) + hw0);
    const float f = sigmf_(__bfloat162float(X[xb + 768]) + hw1);
    const float g = tanhf2(__bfloat162float(X[xb + 1536]) + hw2);
    const float o = sigmf_(__bfloat162float(X[xb + 2304]) + hw3);
    c2 = f * c2 + r * g;
    Hs[((size_t)(base + s) * B_DIM + b) * H2 + H_DIM + j] = __float2bfloat16(o * tanhf2(c2));
  }
  c2state[t] = c2;
}

// ---------------- output: out[i,l] = Hs[i,:] @ Wout + bout (+pad bias) ----------------
__global__ __launch_bounds__(256) void k_out(const __hip_bfloat16* __restrict__ Hs,
                                             const float* __restrict__ Wout,
                                             const float* __restrict__ bout,
                                             const int* __restrict__ tokens,
                                             float* __restrict__ out) {
  __shared__ float rowbuf[8][1536];
  const int r0 = blockIdx.x * 8;
  const int tid = threadIdx.x;
  for (int idx = tid; idx < 8 * 1536; idx += 256) {
    const int rr = idx / 1536, k = idx % 1536;
    rowbuf[rr][k] = __bfloat162float(Hs[(size_t)(r0 + rr) * H2 + k]);
  }
  __syncthreads();
  const int l = tid & 31, rr = tid >> 5;
  float acc = bout[l];
  #pragma unroll 8
  for (int k = 0; k < 1536; ++k) acc += rowbuf[rr][k] * Wout[k * 32 + l];
  const int row = r0 + rr;
  if (l == 0 && tokens[row] == 1) acc += 10000.0f;
  out[(size_t)row * 32 + l] = acc;
}

// ---------------- host launcher ----------------
extern "C" void kernel_launch(void* const* d_in, const int* in_sizes, int n_in,
                              void* d_out, int out_size, void* d_ws, size_t ws_size,
                              hipStream_t stream) {
  const int*   tokens = (const int*)d_in[0];
  const float* emb    = (const float*)d_in[2];
  const float* Wi_f   = (const float*)d_in[3];
  const float* bi_f   = (const float*)d_in[4];
  const float* Wh_f   = (const float*)d_in[5];
  const float* bh_f   = (const float*)d_in[6];
  const float* Wi_b   = (const float*)d_in[7];
  const float* bi_b   = (const float*)d_in[8];
  const float* Wh_b   = (const float*)d_in[9];
  const float* bh_b   = (const float*)d_in[10];
  const float* Wout   = (const float*)d_in[11];
  const float* bout   = (const float*)d_in[12];
  float* out = (float*)d_out;
  char* ws = (char*)d_ws;

  size_t off = 0;
  auto alloc = [&](size_t bytes) { size_t o = off; off += (bytes + 255) & ~(size_t)255; return o; };
  const size_t oHs   = alloc((size_t)M_ROWS * H2 * 2);        // 100.7 MB
  const size_t oX    = alloc((size_t)CM * G4 * 2);            // 50.3 MB
  const size_t oEmb  = alloc((size_t)M_ROWS * E_DIM * 2);     // 33.6 MB
  const size_t oWiT  = alloc((size_t)G4 * E_DIM * 2);         // 3.1 MB
  const size_t oWhTf = alloc((size_t)G4 * H_DIM * 2);         // 4.7 MB
  const size_t oWhP  = alloc((size_t)4 * 1024 * H_DIM * 2);   // 6.3 MB slot-padded
  const size_t oBias = alloc((size_t)G4 * 4);
  const size_t oHbuf = alloc((size_t)2 * B_DIM * WPR * 8);    // 256 KB packed h
  const size_t oCst  = alloc((size_t)B_DIM * H_DIM * 4);
  const size_t oHT   = alloc((size_t)B_DIM * H_DIM * 4);
  const size_t oHTW  = alloc((size_t)B_DIM * G4 * 4);
  const size_t oC2   = alloc((size_t)B_DIM * H_DIM * 4);
  (void)ws_size; (void)in_sizes; (void)n_in; (void)out_size;   // total ~200 MB

  __hip_bfloat16* Hs   = (__hip_bfloat16*)(ws + oHs);
  __hip_bfloat16* X    = (__hip_bfloat16*)(ws + oX);
  __hip_bfloat16* Emb  = (__hip_bfloat16*)(ws + oEmb);
  __hip_bfloat16* WiT  = (__hip_bfloat16*)(ws + oWiT);
  __hip_bfloat16* WhTf = (__hip_bfloat16*)(ws + oWhTf);
  __hip_bfloat16* WhP  = (__hip_bfloat16*)(ws + oWhP);
  float*          Bias = (float*)(ws + oBias);
  ull_t*          Hbuf = (ull_t*)(ws + oHbuf);
  float*          Cst  = (float*)(ws + oCst);
  float*          HT   = (float*)(ws + oHT);
  float*          HTW  = (float*)(ws + oHTW);
  float*          C2   = (float*)(ws + oC2);

  hipMemsetAsync(ws + oHbuf, 0, (size_t)2 * B_DIM * WPR * 8, stream);  // h_0 = 0, tag 0
  hipMemsetAsync(ws + oCst, 0, (size_t)B_DIM * H_DIM * 4, stream);
  hipMemsetAsync(ws + oC2, 0, (size_t)B_DIM * H_DIM * 4, stream);

  k_gather<<<8192, 256, 0, stream>>>(tokens, emb, Emb);
  k_transpose_cast<<<dim3(96, 24), 256, 0, stream>>>(Wh_f, WhTf, 768, 3072);
  k_wpad<<<1536, 256, 0, stream>>>(WhTf, WhP);

  // ---- forward direction: 4 chunks of (GEMM -> scan) ----
  k_transpose_cast<<<dim3(96, 16), 256, 0, stream>>>(Wi_f, WiT, 512, 3072);
  k_bias<<<12, 256, 0, stream>>>(bi_f, bh_f, Bias);
  for (int c = 0; c < 4; ++c) {
    k_gemm_x<<<dim3(24, 64), 256, 0, stream>>>(Emb + (size_t)c * CM * E_DIM, WiT, Bias, X);
    k_fwd_scan<<<64, 256, 0, stream>>>(X, WhP, Hbuf, Hs, Cst, HT, c);
  }

  // ---- backward direction: hT@Wh_b once, then 4 chunks in reverse ----
  k_hTW<<<dim3(12, 64), 256, 0, stream>>>(HT, Wh_b, HTW);
  k_transpose_cast<<<dim3(96, 16), 256, 0, stream>>>(Wi_b, WiT, 512, 3072);
  k_bias<<<12, 256, 0, stream>>>(bi_b, bh_b, Bias);
  for (int c = 3; c >= 0; --c) {
    k_gemm_x<<<dim3(24, 64), 256, 0, stream>>>(Emb + (size_t)c * CM * E_DIM, WiT, Bias, X);
    k_bwd_scan<<<192, 256, 0, stream>>>(X, HTW, Hs, C2, c);
  }

  k_out<<<4096, 256, 0, stream>>>(Hs, Wout, bout, tokens, out);
}